// Round 13
// baseline (22.426 us; speedup 1.0000x reference)
//
#include <hip/hip_runtime.h>
#include <math.h>

#define A_ 64
#define T_ 32
#define B_ 64
#define V_ 12
#define D_ 512
#define TAUF 100.0f
#define NCH 8              // K chunks of 64

// stage buffer (bytes): A_hi[kg8][64][16] 8192 | A_lo 8192 |
//                       B_hi[kg8][48][16] 6144 | B_lo 6144  = 28672 (single buf)
#define AHI 0
#define ALO 8192
#define BHI 16384
#define BLO 22528
#define BUFBYTES 28672

typedef __attribute__((ext_vector_type(8))) short bf16x8;
typedef __attribute__((ext_vector_type(4))) float f32x4;

// truncation split: hi = top 16 bits of f32, lo = trunc(y - hi). ~5 VALU/elem.
__device__ __forceinline__ void splitT(const float4 x0, const float4 x1,
                                       bf16x8& hv, bf16x8& lv, float& ss)
{
    float y[8] = {x0.x, x0.y, x0.z, x0.w, x1.x, x1.y, x1.z, x1.w};
    #pragma unroll
    for (int j = 0; j < 8; ++j) {
        ss += y[j] * y[j];
        unsigned int u = __float_as_uint(y[j]);
        float hf = __uint_as_float(u & 0xffff0000u);
        hv[j] = (short)(u >> 16);
        lv[j] = (short)(__float_as_uint(y[j] - hf) >> 16);
    }
}

// Single kernel, single-buffer + async reg-staged split (T14):
// per chunk: {issue loads k+1 -> regs} | {MFMA k from LDS} | barrier |
// {split+write k+1} | barrier. LDS ~34KB -> 4 blocks/CU (16 waves) so
// staggered blocks keep the LDS pipe fed through each other's barriers.
__global__ __launch_bounds__(256, 4)
void fused_kernel(const float* __restrict__ text,
                  const float* __restrict__ video,
                  const int* __restrict__ mask,
                  float* __restrict__ out)
{
    const int wgid = blockIdx.x;      // 0..511
    const int xcd  = wgid & 7;
    const int i    = wgid >> 3;
    const int bm   = xcd * 4 + (i >> 4);   // 0..31
    const int bn   = i & 15;               // 0..15
    const int tid  = threadIdx.x;     // 0..255
    const int wid  = tid >> 6;
    const int lane = tid & 63;
    const int r16  = lane & 15;
    const int kg4  = lane >> 4;

    __shared__ __align__(16) char stage[BUFBYTES];
    __shared__ float nrmA[8][64];
    __shared__ float nrmB[8][48];
    __shared__ float invA[64];
    __shared__ float invB[48];
    __shared__ int   msh[2][T_];
    __shared__ float v2t_sh[8][V_];
    __shared__ float wv_sh[8][V_];
    __shared__ float stats1[8];

    if (tid < 64) msh[tid >> 5][tid & 31] = mask[(bm * 2 + (tid >> 5)) * T_ + (tid & 31)];

    // pack granule assignments (memory-linear: coalesced global reads)
    const int arow0 = tid >> 3, akg = tid & 7;
    const int arow1 = arow0 + 32;
    const float* asrc0 = text + ((size_t)(bm * 64 + arow0)) * D_ + akg * 8;
    const float* asrc1 = text + ((size_t)(bm * 64 + arow1)) * D_ + akg * 8;
    const int brow0 = tid >> 3, bkg = tid & 7;        // valid for tid<192
    const int brow1 = brow0 + 24;
    const float* bsrc0 = video + ((size_t)(bn * 48 + brow0)) * D_ + bkg * 8;
    const float* bsrc1 = video + ((size_t)(bn * 48 + brow1)) * D_ + bkg * 8;

    // swizzled LDS byte offsets for pack writes
    const int adst0 = (akg * 64 + (arow0 ^ akg)) * 16;
    const int adst1 = (akg * 64 + (arow1 ^ akg)) * 16;
    const int bdst0 = BHI + (bkg * 48 + (brow0 ^ bkg)) * 16;
    const int bdst1 = BHI + (bkg * 48 + (brow1 ^ bkg)) * 16;

    float ssA0 = 0.f, ssA1 = 0.f, ssB0 = 0.f, ssB1 = 0.f;

    // in-flight load registers for the async stage split
    float4 ra0[2], ra1[2], rb0[2], rb1[2];

    auto LOAD = [&](int k) {
        const float4* s0 = (const float4*)(asrc0 + k * 64);
        const float4* s1 = (const float4*)(asrc1 + k * 64);
        ra0[0] = s0[0]; ra0[1] = s0[1];
        ra1[0] = s1[0]; ra1[1] = s1[1];
        if (tid < 192) {
            const float4* t0 = (const float4*)(bsrc0 + k * 64);
            const float4* t1 = (const float4*)(bsrc1 + k * 64);
            rb0[0] = t0[0]; rb0[1] = t0[1];
            rb1[0] = t1[0]; rb1[1] = t1[1];
        }
    };
    auto WRITE = [&]() {
        bf16x8 hv, lv;
        splitT(ra0[0], ra0[1], hv, lv, ssA0);
        *(bf16x8*)(stage + adst0)       = hv;
        *(bf16x8*)(stage + ALO + adst0) = lv;
        splitT(ra1[0], ra1[1], hv, lv, ssA1);
        *(bf16x8*)(stage + adst1)       = hv;
        *(bf16x8*)(stage + ALO + adst1) = lv;
        if (tid < 192) {
            splitT(rb0[0], rb0[1], hv, lv, ssB0);
            *(bf16x8*)(stage + bdst0)               = hv;
            *(bf16x8*)(stage + (BLO - BHI) + bdst0) = lv;
            splitT(rb1[0], rb1[1], hv, lv, ssB1);
            *(bf16x8*)(stage + bdst1)               = hv;
            *(bf16x8*)(stage + (BLO - BHI) + bdst1) = lv;
        }
    };

    // swizzled fragment byte offsets (s = k-step 0/1 within chunk)
    const int rowa = wid * 16 + r16;
    int aoff[2], boff[2][3];
    #pragma unroll
    for (int s = 0; s < 2; ++s) {
        int kg = s * 4 + kg4;
        aoff[s] = (kg * 64 + (rowa ^ kg)) * 16;
        #pragma unroll
        for (int c = 0; c < 3; ++c) {
            int rowb = c * 16 + r16;
            boff[s][c] = BHI + (kg * 48 + (rowb ^ kg)) * 16;
        }
    }

    f32x4 acc0 = {0.f, 0.f, 0.f, 0.f};
    f32x4 acc1 = {0.f, 0.f, 0.f, 0.f};
    f32x4 acc2 = {0.f, 0.f, 0.f, 0.f};

    LOAD(0);
    WRITE();
    __syncthreads();

    #pragma unroll 2
    for (int k = 0; k < NCH; ++k) {
        if (k + 1 < NCH) LOAD(k + 1);          // issue; latency hides under MFMA
        #pragma unroll
        for (int s = 0; s < 2; ++s) {
            bf16x8 aH  = *(const bf16x8*)(stage + aoff[s]);
            bf16x8 aL  = *(const bf16x8*)(stage + ALO + aoff[s]);
            bf16x8 bH0 = *(const bf16x8*)(stage + boff[s][0]);
            bf16x8 bL0 = *(const bf16x8*)(stage + (BLO - BHI) + boff[s][0]);
            bf16x8 bH1 = *(const bf16x8*)(stage + boff[s][1]);
            bf16x8 bL1 = *(const bf16x8*)(stage + (BLO - BHI) + boff[s][1]);
            bf16x8 bH2 = *(const bf16x8*)(stage + boff[s][2]);
            bf16x8 bL2 = *(const bf16x8*)(stage + (BLO - BHI) + boff[s][2]);
            acc0 = __builtin_amdgcn_mfma_f32_16x16x32_bf16(aH, bH0, acc0, 0, 0, 0);
            acc1 = __builtin_amdgcn_mfma_f32_16x16x32_bf16(aH, bH1, acc1, 0, 0, 0);
            acc2 = __builtin_amdgcn_mfma_f32_16x16x32_bf16(aH, bH2, acc2, 0, 0, 0);
            acc0 = __builtin_amdgcn_mfma_f32_16x16x32_bf16(aH, bL0, acc0, 0, 0, 0);
            acc1 = __builtin_amdgcn_mfma_f32_16x16x32_bf16(aH, bL1, acc1, 0, 0, 0);
            acc2 = __builtin_amdgcn_mfma_f32_16x16x32_bf16(aH, bL2, acc2, 0, 0, 0);
            acc0 = __builtin_amdgcn_mfma_f32_16x16x32_bf16(aL, bH0, acc0, 0, 0, 0);
            acc1 = __builtin_amdgcn_mfma_f32_16x16x32_bf16(aL, bH1, acc1, 0, 0, 0);
            acc2 = __builtin_amdgcn_mfma_f32_16x16x32_bf16(aL, bH2, acc2, 0, 0, 0);
        }
        __syncthreads();                       // stage reads done
        if (k + 1 < NCH) {
            WRITE();                           // vmcnt-wait + split + LDS write
            __syncthreads();                   // stage ready for next chunk
        }
    }

    // ---- norm reduction: 8 partials per row -> inverse norms ----
    nrmA[akg][arow0] = ssA0;
    nrmA[akg][arow1] = ssA1;
    if (tid < 192) { nrmB[bkg][brow0] = ssB0; nrmB[bkg][brow1] = ssB1; }
    __syncthreads();
    if (tid < 64) {
        float s = 0.f;
        #pragma unroll
        for (int j = 0; j < 8; ++j) s += nrmA[j][tid];
        invA[tid] = 1.0f / fmaxf(sqrtf(s), 1e-6f);
    } else if (tid < 112) {
        int r = tid - 64;
        float s = 0.f;
        #pragma unroll
        for (int j = 0; j < 8; ++j) s += nrmB[j][r];
        invB[r] = 1.0f / fmaxf(sqrtf(s), 1e-6f);
    }
    __syncthreads();

    // ---- scatter C (scaled by invA*invB) into Lf[al][bl][t][v] ----
    float* Lf = (float*)&stage[0];         // 12288 B overlay
    {
        // C layout: row = (lane>>4)*4 + reg, col = lane&15
        #pragma unroll
        for (int r = 0; r < 4; ++r) {
            int Mrow0 = wid * 16 + kg4 * 4 + r;
            int al = Mrow0 >> 5, t = Mrow0 & 31;
            float ia = invA[Mrow0];
            int c0 = r16, c1 = 16 + r16, c2 = 32 + r16;
            int bl0 = c0 / 12, bl1 = c1 / 12, bl2 = c2 / 12;
            Lf[((al * 4 + bl0) * T_ + t) * V_ + (c0 - bl0 * 12)] = acc0[r] * ia * invB[c0];
            Lf[((al * 4 + bl1) * T_ + t) * V_ + (c1 - bl1 * 12)] = acc1[r] * ia * invB[c1];
            Lf[((al * 4 + bl2) * T_ + t) * V_ + (c2 - bl2 * 12)] = acc2[r] * ia * invB[c2];
        }
    }
    __syncthreads();

    // ---- softmax phases: half-wave (32 lanes) per (al, bl) pair ----
    const int p   = tid >> 5;          // 0..7
    const int l32 = tid & 31;
    const int al  = p >> 2, bl = p & 3;
    const float* Lrow = &Lf[((al * 4 + bl) * T_ + l32) * V_];

    // vps1 row softmax -> t2v (register)
    float t2v_val;
    {
        float l[V_];
        #pragma unroll
        for (int j = 0; j < V_; ++j) l[j] = Lrow[j];
        if (msh[al][l32]) {
            float m = -1e30f;
            #pragma unroll
            for (int j = 0; j < V_; ++j) m = fmaxf(m, l[j]);
            float s = 0.f, num = 0.f;
            #pragma unroll
            for (int j = 0; j < V_; ++j) {
                float e = expf(TAUF * (l[j] - m));
                s += e; num += e * l[j];
            }
            t2v_val = num / s;
        } else {
            // masked row: softmax of zeros = uniform -> mean of raw logits
            float s = 0.f;
            #pragma unroll
            for (int j = 0; j < V_; ++j) s += l[j];
            t2v_val = s * (1.0f / V_);
        }
    }

    // tps2 weights via width-32 shuffles; keep w2, W2 in registers
    bool  ex = (t2v_val == 0.0f);
    float xm = ex ? -1e30f : t2v_val;
    #pragma unroll
    for (int m = 16; m >= 1; m >>= 1) xm = fmaxf(xm, __shfl_xor(xm, m, 32));
    float w2 = ex ? 0.0f : expf(TAUF * (t2v_val - xm));
    float W2 = w2;
    #pragma unroll
    for (int m = 16; m >= 1; m >>= 1) W2 += __shfl_xor(W2, m, 32);

    // tps1 masked column softmax -> v2t_sh
    if (l32 < V_) {
        float m = -1e30f;
        for (int j = 0; j < T_; ++j) {
            float Lraw = Lf[((al * 4 + bl) * T_ + j) * V_ + l32];
            float Lm = msh[al][j] ? Lraw : 0.0f;
            if (Lm != 0.0f) m = fmaxf(m, Lm);
        }
        float s = 0.f, num = 0.f;
        for (int j = 0; j < T_; ++j) {
            float Lraw = Lf[((al * 4 + bl) * T_ + j) * V_ + l32];
            float Lm = msh[al][j] ? Lraw : 0.0f;
            if (Lm != 0.0f) {
                float e = expf(TAUF * (Lm - m));
                s += e; num += e * Lraw;
            }
        }
        v2t_sh[p][l32] = num / s;
    }
    __syncthreads();

    // vps2 weights
    if (l32 < V_) {
        float m = -1e30f;
        #pragma unroll
        for (int j = 0; j < V_; ++j) m = fmaxf(m, v2t_sh[p][j]);
        float s = 0.f;
        #pragma unroll
        for (int j = 0; j < V_; ++j) s += expf(TAUF * (v2t_sh[p][j] - m));
        wv_sh[p][l32] = expf(TAUF * (v2t_sh[p][l32] - m));
        if (l32 == 0) stats1[p] = s;
    }
    __syncthreads();

    // out = sum_{t,v} w2[t]*wv[v]*L[t,v] / (W2*Wv)
    {
        float pD = 0.f;
        #pragma unroll
        for (int j = 0; j < V_; ++j) pD += wv_sh[p][j] * Lrow[j];
        pD *= w2;
        #pragma unroll
        for (int m = 16; m >= 1; m >>= 1) pD += __shfl_xor(pD, m, 32);
        if (l32 == 0)
            out[(bm * 2 + al) * B_ + bn * 4 + bl] = pD / (W2 * stats1[p]);
    }
}

extern "C" void kernel_launch(void* const* d_in, const int* in_sizes, int n_in,
                              void* d_out, int out_size, void* d_ws, size_t ws_size,
                              hipStream_t stream) {
    const float* text  = (const float*)d_in[0];
    const float* video = (const float*)d_in[1];
    const int*   mask  = (const int*)d_in[2];
    float* out = (float*)d_out;

    fused_kernel<<<512, 256, 0, stream>>>(text, video, mask, out);
}

// Round 14
// 20.802 us; speedup vs baseline: 1.0781x; 1.0781x over previous
//
#include <hip/hip_runtime.h>
#include <math.h>

#define A_ 64
#define T_ 32
#define B_ 64
#define V_ 12
#define D_ 512
#define TAUF 100.0f
#define NCH 8              // K chunks of 64

// stage buffer (bytes): A_hi[kg8][64][16] 8192 | A_lo 8192 |
//                       B_hi[kg8][48][16] 6144 | B_lo 6144  = 28672, x2 dbuf
#define ALO 8192
#define BHI 16384
#define BLO 22528
#define BUFBYTES 28672

typedef __attribute__((ext_vector_type(8))) short bf16x8;
typedef __attribute__((ext_vector_type(4))) float f32x4;

// truncation split: hi = top 16 bits of f32, lo = trunc(y - hi). ~5 VALU/elem.
__device__ __forceinline__ void splitT(const float4 x0, const float4 x1,
                                       bf16x8& hv, bf16x8& lv, float& ss)
{
    float y[8] = {x0.x, x0.y, x0.z, x0.w, x1.x, x1.y, x1.z, x1.w};
    #pragma unroll
    for (int j = 0; j < 8; ++j) {
        ss += y[j] * y[j];
        unsigned int u = __float_as_uint(y[j]);
        float hf = __uint_as_float(u & 0xffff0000u);
        hv[j] = (short)(u >> 16);
        lv[j] = (short)(__float_as_uint(y[j] - hf) >> 16);
    }
}

struct RegSet { float4 a0[2], a1[2], b0[2], b1[2]; };

// Single kernel: 64x48 C-tile (2a x 4b), 4 waves, dbuf LDS + 2-deep register
// pipeline: iter k = { MFMA(buf k) | LOAD(k+2)->regs | WRITE(k+1)->buf k+1 |
// barrier }. WRITE's data was loaded a full chunk earlier -> vmcnt free.
__global__ __launch_bounds__(256)
void fused_kernel(const float* __restrict__ text,
                  const float* __restrict__ video,
                  const int* __restrict__ mask,
                  float* __restrict__ out)
{
    const int wgid = blockIdx.x;      // 0..511
    const int xcd  = wgid & 7;
    const int i    = wgid >> 3;
    const int bm   = xcd * 4 + (i >> 4);   // 0..31
    const int bn   = i & 15;               // 0..15
    const int tid  = threadIdx.x;     // 0..255
    const int wid  = tid >> 6;
    const int lane = tid & 63;
    const int r16  = lane & 15;
    const int kg4  = lane >> 4;

    __shared__ __align__(16) char stage[2][BUFBYTES];
    __shared__ float nrmA[8][64];
    __shared__ float nrmB[8][48];
    __shared__ float invA[64];
    __shared__ float invB[48];
    __shared__ int   msh[2][T_];
    __shared__ float v2t_sh[8][V_];
    __shared__ float wv_sh[8][V_];
    __shared__ float stats1[8];

    if (tid < 64) msh[tid >> 5][tid & 31] = mask[(bm * 2 + (tid >> 5)) * T_ + (tid & 31)];

    // pack granule assignments (memory-linear: coalesced global reads)
    const int arow0 = tid >> 3, akg = tid & 7;
    const int arow1 = arow0 + 32;
    const float* asrc0 = text + ((size_t)(bm * 64 + arow0)) * D_ + akg * 8;
    const float* asrc1 = text + ((size_t)(bm * 64 + arow1)) * D_ + akg * 8;
    const int brow0 = tid >> 3, bkg = tid & 7;        // valid for tid<192
    const int brow1 = brow0 + 24;
    const float* bsrc0 = video + ((size_t)(bn * 48 + brow0)) * D_ + bkg * 8;
    const float* bsrc1 = video + ((size_t)(bn * 48 + brow1)) * D_ + bkg * 8;

    // swizzled LDS byte offsets for pack writes
    const int adst0 = (akg * 64 + (arow0 ^ akg)) * 16;
    const int adst1 = (akg * 64 + (arow1 ^ akg)) * 16;
    const int bdst0 = BHI + (bkg * 48 + (brow0 ^ bkg)) * 16;
    const int bdst1 = BHI + (bkg * 48 + (brow1 ^ bkg)) * 16;

    float ssA0 = 0.f, ssA1 = 0.f, ssB0 = 0.f, ssB1 = 0.f;

    RegSet rs0, rs1;      // two in-flight chunks (even/odd)

    auto LOAD = [&](RegSet& R, int k) {
        const float4* s0 = (const float4*)(asrc0 + k * 64);
        const float4* s1 = (const float4*)(asrc1 + k * 64);
        R.a0[0] = s0[0]; R.a0[1] = s0[1];
        R.a1[0] = s1[0]; R.a1[1] = s1[1];
        if (tid < 192) {
            const float4* t0 = (const float4*)(bsrc0 + k * 64);
            const float4* t1 = (const float4*)(bsrc1 + k * 64);
            R.b0[0] = t0[0]; R.b0[1] = t0[1];
            R.b1[0] = t1[0]; R.b1[1] = t1[1];
        }
    };
    auto WRITE = [&](RegSet& R, int bufi) {
        char* buf = stage[bufi];
        bf16x8 hv, lv;
        splitT(R.a0[0], R.a0[1], hv, lv, ssA0);
        *(bf16x8*)(buf + adst0)       = hv;
        *(bf16x8*)(buf + ALO + adst0) = lv;
        splitT(R.a1[0], R.a1[1], hv, lv, ssA1);
        *(bf16x8*)(buf + adst1)       = hv;
        *(bf16x8*)(buf + ALO + adst1) = lv;
        if (tid < 192) {
            splitT(R.b0[0], R.b0[1], hv, lv, ssB0);
            *(bf16x8*)(buf + bdst0)               = hv;
            *(bf16x8*)(buf + (BLO - BHI) + bdst0) = lv;
            splitT(R.b1[0], R.b1[1], hv, lv, ssB1);
            *(bf16x8*)(buf + bdst1)               = hv;
            *(bf16x8*)(buf + (BLO - BHI) + bdst1) = lv;
        }
    };

    // swizzled fragment byte offsets (s = k-step 0/1 within chunk)
    const int rowa = wid * 16 + r16;
    int aoff[2], boff[2][3];
    #pragma unroll
    for (int s = 0; s < 2; ++s) {
        int kg = s * 4 + kg4;
        aoff[s] = (kg * 64 + (rowa ^ kg)) * 16;
        #pragma unroll
        for (int c = 0; c < 3; ++c) {
            int rowb = c * 16 + r16;
            boff[s][c] = BHI + (kg * 48 + (rowb ^ kg)) * 16;
        }
    }

    f32x4 acc0 = {0.f, 0.f, 0.f, 0.f};
    f32x4 acc1 = {0.f, 0.f, 0.f, 0.f};
    f32x4 acc2 = {0.f, 0.f, 0.f, 0.f};

    LOAD(rs0, 0);
    WRITE(rs0, 0);
    LOAD(rs1, 1);
    __syncthreads();

    #pragma unroll
    for (int k = 0; k < NCH; ++k) {
        if (k + 2 < NCH) LOAD((k & 1) ? rs1 : rs0, k + 2);   // refill just-freed set
        const char* buf = stage[k & 1];
        #pragma unroll
        for (int s = 0; s < 2; ++s) {
            bf16x8 aH  = *(const bf16x8*)(buf + aoff[s]);
            bf16x8 aL  = *(const bf16x8*)(buf + ALO + aoff[s]);
            bf16x8 bH0 = *(const bf16x8*)(buf + boff[s][0]);
            bf16x8 bL0 = *(const bf16x8*)(buf + (BLO - BHI) + boff[s][0]);
            bf16x8 bH1 = *(const bf16x8*)(buf + boff[s][1]);
            bf16x8 bL1 = *(const bf16x8*)(buf + (BLO - BHI) + boff[s][1]);
            bf16x8 bH2 = *(const bf16x8*)(buf + boff[s][2]);
            bf16x8 bL2 = *(const bf16x8*)(buf + (BLO - BHI) + boff[s][2]);
            acc0 = __builtin_amdgcn_mfma_f32_16x16x32_bf16(aH, bH0, acc0, 0, 0, 0);
            acc1 = __builtin_amdgcn_mfma_f32_16x16x32_bf16(aH, bH1, acc1, 0, 0, 0);
            acc2 = __builtin_amdgcn_mfma_f32_16x16x32_bf16(aH, bH2, acc2, 0, 0, 0);
            acc0 = __builtin_amdgcn_mfma_f32_16x16x32_bf16(aH, bL0, acc0, 0, 0, 0);
            acc1 = __builtin_amdgcn_mfma_f32_16x16x32_bf16(aH, bL1, acc1, 0, 0, 0);
            acc2 = __builtin_amdgcn_mfma_f32_16x16x32_bf16(aH, bL2, acc2, 0, 0, 0);
            acc0 = __builtin_amdgcn_mfma_f32_16x16x32_bf16(aL, bH0, acc0, 0, 0, 0);
            acc1 = __builtin_amdgcn_mfma_f32_16x16x32_bf16(aL, bH1, acc1, 0, 0, 0);
            acc2 = __builtin_amdgcn_mfma_f32_16x16x32_bf16(aL, bH2, acc2, 0, 0, 0);
        }
        if (k + 1 < NCH) WRITE((k & 1) ? rs0 : rs1, (k + 1) & 1);  // data loaded 1 chunk ago
        __syncthreads();
    }

    // ---- norm reduction: 8 partials per row -> inverse norms ----
    nrmA[akg][arow0] = ssA0;
    nrmA[akg][arow1] = ssA1;
    if (tid < 192) { nrmB[bkg][brow0] = ssB0; nrmB[bkg][brow1] = ssB1; }
    __syncthreads();
    if (tid < 64) {
        float s = 0.f;
        #pragma unroll
        for (int j = 0; j < 8; ++j) s += nrmA[j][tid];
        invA[tid] = 1.0f / fmaxf(sqrtf(s), 1e-6f);
    } else if (tid < 112) {
        int r = tid - 64;
        float s = 0.f;
        #pragma unroll
        for (int j = 0; j < 8; ++j) s += nrmB[j][r];
        invB[r] = 1.0f / fmaxf(sqrtf(s), 1e-6f);
    }
    __syncthreads();

    // ---- scatter C (scaled by invA*invB) into Lf[al][bl][t][v] ----
    float* Lf = (float*)&stage[0][0];      // 12288 B overlay
    {
        // C layout: row = (lane>>4)*4 + reg, col = lane&15
        #pragma unroll
        for (int r = 0; r < 4; ++r) {
            int Mrow0 = wid * 16 + kg4 * 4 + r;
            int al = Mrow0 >> 5, t = Mrow0 & 31;
            float ia = invA[Mrow0];
            int c0 = r16, c1 = 16 + r16, c2 = 32 + r16;
            int bl0 = c0 / 12, bl1 = c1 / 12, bl2 = c2 / 12;
            Lf[((al * 4 + bl0) * T_ + t) * V_ + (c0 - bl0 * 12)] = acc0[r] * ia * invB[c0];
            Lf[((al * 4 + bl1) * T_ + t) * V_ + (c1 - bl1 * 12)] = acc1[r] * ia * invB[c1];
            Lf[((al * 4 + bl2) * T_ + t) * V_ + (c2 - bl2 * 12)] = acc2[r] * ia * invB[c2];
        }
    }
    __syncthreads();

    // ---- softmax phases: half-wave (32 lanes) per (al, bl) pair ----
    const int p   = tid >> 5;          // 0..7
    const int l32 = tid & 31;
    const int al  = p >> 2, bl = p & 3;
    const float* Lrow = &Lf[((al * 4 + bl) * T_ + l32) * V_];

    // vps1 row softmax -> t2v (register)
    float t2v_val;
    {
        float l[V_];
        #pragma unroll
        for (int j = 0; j < V_; ++j) l[j] = Lrow[j];
        if (msh[al][l32]) {
            float m = -1e30f;
            #pragma unroll
            for (int j = 0; j < V_; ++j) m = fmaxf(m, l[j]);
            float s = 0.f, num = 0.f;
            #pragma unroll
            for (int j = 0; j < V_; ++j) {
                float e = expf(TAUF * (l[j] - m));
                s += e; num += e * l[j];
            }
            t2v_val = num / s;
        } else {
            // masked row: softmax of zeros = uniform -> mean of raw logits
            float s = 0.f;
            #pragma unroll
            for (int j = 0; j < V_; ++j) s += l[j];
            t2v_val = s * (1.0f / V_);
        }
    }

    // tps2 weights via width-32 shuffles; keep w2, W2 in registers
    bool  ex = (t2v_val == 0.0f);
    float xm = ex ? -1e30f : t2v_val;
    #pragma unroll
    for (int m = 16; m >= 1; m >>= 1) xm = fmaxf(xm, __shfl_xor(xm, m, 32));
    float w2 = ex ? 0.0f : expf(TAUF * (t2v_val - xm));
    float W2 = w2;
    #pragma unroll
    for (int m = 16; m >= 1; m >>= 1) W2 += __shfl_xor(W2, m, 32);

    // tps1 masked column softmax -> v2t_sh
    if (l32 < V_) {
        float m = -1e30f;
        for (int j = 0; j < T_; ++j) {
            float Lraw = Lf[((al * 4 + bl) * T_ + j) * V_ + l32];
            float Lm = msh[al][j] ? Lraw : 0.0f;
            if (Lm != 0.0f) m = fmaxf(m, Lm);
        }
        float s = 0.f, num = 0.f;
        for (int j = 0; j < T_; ++j) {
            float Lraw = Lf[((al * 4 + bl) * T_ + j) * V_ + l32];
            float Lm = msh[al][j] ? Lraw : 0.0f;
            if (Lm != 0.0f) {
                float e = expf(TAUF * (Lm - m));
                s += e; num += e * Lraw;
            }
        }
        v2t_sh[p][l32] = num / s;
    }
    __syncthreads();

    // vps2 weights
    if (l32 < V_) {
        float m = -1e30f;
        #pragma unroll
        for (int j = 0; j < V_; ++j) m = fmaxf(m, v2t_sh[p][j]);
        float s = 0.f;
        #pragma unroll
        for (int j = 0; j < V_; ++j) s += expf(TAUF * (v2t_sh[p][j] - m));
        wv_sh[p][l32] = expf(TAUF * (v2t_sh[p][l32] - m));
        if (l32 == 0) stats1[p] = s;
    }
    __syncthreads();

    // out = sum_{t,v} w2[t]*wv[v]*L[t,v] / (W2*Wv)
    {
        float pD = 0.f;
        #pragma unroll
        for (int j = 0; j < V_; ++j) pD += wv_sh[p][j] * Lrow[j];
        pD *= w2;
        #pragma unroll
        for (int m = 16; m >= 1; m >>= 1) pD += __shfl_xor(pD, m, 32);
        if (l32 == 0)
            out[(bm * 2 + al) * B_ + bn * 4 + bl] = pD / (W2 * stats1[p]);
    }
}

extern "C" void kernel_launch(void* const* d_in, const int* in_sizes, int n_in,
                              void* d_out, int out_size, void* d_ws, size_t ws_size,
                              hipStream_t stream) {
    const float* text  = (const float*)d_in[0];
    const float* video = (const float*)d_in[1];
    const int*   mask  = (const int*)d_in[2];
    float* out = (float*)d_out;

    fused_kernel<<<512, 256, 0, stream>>>(text, video, mask, out);
}